// Round 5
// baseline (907.699 us; speedup 1.0000x reference)
//
#include <hip/hip_runtime.h>
#include <hip/hip_bf16.h>
#include <stdint.h>

#define DEV_INLINE __device__ __forceinline__

typedef __attribute__((ext_vector_type(4))) float f32x4;
typedef __attribute__((ext_vector_type(8))) __bf16 bf16x8;
typedef __attribute__((ext_vector_type(8))) unsigned short u16x8;

// problem dims
constexpr int Hh = 32, KVc = 8, Dd = 128, Gg = 4, Nn = 16;

DEV_INLINE unsigned short f32_to_bf16(float f) {
  unsigned u = __float_as_uint(f);
  u += 0x7fffu + ((u >> 16) & 1u);   // round-to-nearest-even
  return (unsigned short)(u >> 16);
}
DEV_INLINE float bf16_lo(unsigned u) { return __uint_as_float(u << 16); }
DEV_INLINE float bf16_hi(unsigned u) { return __uint_as_float(u & 0xffff0000u); }

// ---------------- cast f32 -> bf16 (optionally scaled) ----------------
__global__ void cast_f32_bf16_kernel(const float* __restrict__ src,
                                     unsigned short* __restrict__ dst,
                                     int n4, float scale) {
  int i = blockIdx.x * blockDim.x + threadIdx.x;
  int stride = gridDim.x * blockDim.x;
  const f32x4* s4 = reinterpret_cast<const f32x4*>(src);
  ushort4* d4 = reinterpret_cast<ushort4*>(dst);
  for (; i < n4; i += stride) {
    f32x4 v = s4[i];
    ushort4 o;
    o.x = f32_to_bf16(v.x * scale);
    o.y = f32_to_bf16(v.y * scale);
    o.z = f32_to_bf16(v.z * scale);
    o.w = f32_to_bf16(v.w * scale);
    d4[i] = o;
  }
}

// ---------------- GEMM: C[M][N] = A[M][K] * B[N][K]^T ----------------
// m201-template reconstruction: 256x256 tile, BK=64, 512 threads (2m x 4n
// waves), STRIDED wave tiling (m-frag row = m*32+wm*16, n-frag col =
// n*64+wn*16) so phase quadrant (mh,nh) touches exactly one A-half and one
// B-half. 2-deep LDS double buffer of 2 halves per operand (128 KiB). 8
// phases per 2 K-tiles; per phase: {12 ds_read || stage 1 half-tile ->
// s_barrier -> lgkmcnt(0)+sched_barrier -> setprio+16 MFMA -> vmcnt(6) ->
// s_barrier}. Half-of-row XOR swizzle (phys16Bslot = logical ^ (row&7)),
// applied inverse on the global staging source (linear DMA dest).
template <bool OUT_BF16>
__global__ __launch_bounds__(512) void gemm256_kernel(
    const unsigned short* __restrict__ A,   // [M][K] bf16
    const unsigned short* __restrict__ Bw,  // [N][K] bf16
    void* __restrict__ Cout,                // [M][N] f32 or bf16
    int M, int N, int K) {
  __shared__ alignas(16) unsigned short Als[2][2][8192];  // [buf][half] 16KB
  __shared__ alignas(16) unsigned short Bls[2][2][8192];
  const int tid = threadIdx.x;
  const int wave = tid >> 6, lane = tid & 63;
  const int wm = wave >> 2, wn = wave & 3;       // 2 x 4 wave grid
  const int r15 = lane & 15, lh = lane >> 4;
  const int psl0 = (lh ^ (r15 & 7)) << 4;        // kk=0 phys slot (bytes)
  const int psl1 = ((4 + lh) ^ (r15 & 7)) << 4;  // kk=1
  const int aoff = (wm * 16 + r15) << 7;         // byte base within A-half
  const int boff = (wn * 16 + r15) << 7;         // byte base within B-half

  // XCD-aware block swizzle (T1); all our grids are % 8 == 0
  const int ntn = N >> 8;
  const int nwg = gridDim.x, bid = blockIdx.x;
  const int swz = (bid & 7) * (nwg >> 3) + (bid >> 3);
  const int tm = swz / ntn, tn = swz - tm * ntn;

  const unsigned short* Abase = A + (long)tm * 256 * K;
  const unsigned short* Bbase = Bw + (long)tn * 256 * K;
  const int ktiles = K >> 6;      // BK=64 (4096->64, 1024->16), always even
  const int iters = ktiles >> 1;

  // stage one 128x64 half-tile (16 KB, 2 loads/thread); linear DMA dest,
  // inverse-swizzled global source. chunk c: row=c>>3, physslot=c&7,
  // logical k-group = (c&7) ^ (row&7).
  auto stageh = [&](const unsigned short* gbase, unsigned short* lhalf, int t,
                    int h) {
#pragma unroll
    for (int j = 0; j < 2; ++j) {
      int c = (j << 9) + tid;
      int row = c >> 3;
      int sl = (c & 7) ^ (row & 7);
      const unsigned short* g =
          gbase + (long)((h << 7) + row) * K + (t << 6) + (sl << 3);
      int ldsoff = ((j << 9) + (wave << 6)) << 4;  // wave-uniform base
      __builtin_amdgcn_global_load_lds(
          (const __attribute__((address_space(1))) unsigned int*)g,
          (__attribute__((address_space(3))) unsigned int*)((char*)lhalf +
                                                            ldsoff),
          16, 0, 0);
    }
  };

  f32x4 acc[8][4];
#pragma unroll
  for (int m = 0; m < 8; ++m)
#pragma unroll
    for (int n = 0; n < 4; ++n) acc[m][n] = {0.f, 0.f, 0.f, 0.f};

  // prologue: stage stream h=0..5 = {Ah0(0),Bh0(0),Bh1(0),Ah1(0),Ah0(1),
  // Bh0(1)}; wait tile-0 (8 oldest loads) landed.
  stageh(Abase, Als[0][0], 0, 0);
  stageh(Bbase, Bls[0][0], 0, 0);
  stageh(Bbase, Bls[0][1], 0, 1);
  stageh(Abase, Als[0][1], 0, 1);
  stageh(Abase, Als[1][0], 1, 0);
  stageh(Bbase, Bls[1][0], 1, 0);
  asm volatile("s_waitcnt vmcnt(4)" ::: "memory");
  __builtin_amdgcn_s_barrier();

  for (int i = 0; i < iters; ++i) {
    const bool last = (i == iters - 1);
#pragma unroll
    for (int ti = 0; ti < 2; ++ti) {
      const int t = 2 * i + ti;
#pragma unroll
      for (int q = 0; q < 4; ++q) {      // quadrant: mh = q>>1, nh = q&1
        const int mh = q >> 1, nh = q & 1;
        const char* Ac = (const char*)Als[t & 1][mh];
        const char* Bc = (const char*)Bls[t & 1][nh];
        bf16x8 af[4][2], bf[2][2];
#pragma unroll
        for (int m = 0; m < 4; ++m) {
          af[m][0] = *reinterpret_cast<const bf16x8*>(Ac + aoff + m * 4096 + psl0);
          af[m][1] = *reinterpret_cast<const bf16x8*>(Ac + aoff + m * 4096 + psl1);
        }
#pragma unroll
        for (int n = 0; n < 2; ++n) {
          bf[n][0] = *reinterpret_cast<const bf16x8*>(Bc + boff + n * 8192 + psl0);
          bf[n][1] = *reinterpret_cast<const bf16x8*>(Bc + boff + n * 8192 + psl1);
        }
        // stage half-tile 6 phases ahead in the stream
        {
          const int g = (t << 2) + q;
          const int hh = g + 6, th = hh >> 2, hj = hh & 3;
          if (th < ktiles) {
            if (hj == 0)      stageh(Abase, Als[th & 1][0], th, 0);
            else if (hj == 1) stageh(Bbase, Bls[th & 1][0], th, 0);
            else if (hj == 2) stageh(Bbase, Bls[th & 1][1], th, 1);
            else              stageh(Abase, Als[th & 1][1], th, 1);
          }
        }
        __builtin_amdgcn_s_barrier();
        asm volatile("s_waitcnt lgkmcnt(0)" ::: "memory");
        __builtin_amdgcn_sched_barrier(0);
        __builtin_amdgcn_s_setprio(1);
#pragma unroll
        for (int m = 0; m < 4; ++m)
#pragma unroll
          for (int n = 0; n < 2; ++n) {
            acc[mh * 4 + m][nh * 2 + n] = __builtin_amdgcn_mfma_f32_16x16x32_bf16(
                af[m][0], bf[n][0], acc[mh * 4 + m][nh * 2 + n], 0, 0, 0);
            acc[mh * 4 + m][nh * 2 + n] = __builtin_amdgcn_mfma_f32_16x16x32_bf16(
                af[m][1], bf[n][1], acc[mh * 4 + m][nh * 2 + n], 0, 0, 0);
          }
        __builtin_amdgcn_s_setprio(0);
        __builtin_amdgcn_sched_barrier(0);
        if (last) asm volatile("s_waitcnt vmcnt(0)" ::: "memory");
        else      asm volatile("s_waitcnt vmcnt(6)" ::: "memory");
        __builtin_amdgcn_s_barrier();
      }
    }
  }

  // epilogue: strided tiling; 16x16 C/D: col = lane&15, row = (lane>>4)*4+r
#pragma unroll
  for (int m = 0; m < 8; ++m) {
#pragma unroll
    for (int n = 0; n < 4; ++n) {
      long r0 = (long)tm * 256 + m * 32 + wm * 16 + lh * 4;
      long c0 = (long)tn * 256 + n * 64 + wn * 16 + r15;
#pragma unroll
      for (int r = 0; r < 4; ++r) {
        float v = acc[m][n][r];
        if constexpr (OUT_BF16)
          ((unsigned short*)Cout)[(r0 + r) * N + c0] = f32_to_bf16(v);
        else
          ((float*)Cout)[(r0 + r) * N + c0] = v;
      }
    }
  }
}

// ---------------- grouped neighbor attention ----------------
// one wave per (b*s, kv); lane = g*16 + i
__global__ __launch_bounds__(256) void attn_kernel(
    const unsigned short* __restrict__ Q,   // [B*S][H*D] bf16 (pre-scaled)
    const unsigned short* __restrict__ Kf,  // [B*S*N][KV*D] bf16
    const unsigned short* __restrict__ Vf,  // [B*S*N][KV*D] bf16
    unsigned short* __restrict__ O) {       // [B*S][H*D] bf16
  const int tid = threadIdx.x;
  const int wave = tid >> 6;
  const int lane = tid & 63;
  const int sl = blockIdx.x * 4 + wave;  // [0, B*S*KV)
  const int bs = sl >> 3;
  const int kv = sl & 7;
  const int g = lane >> 4;
  const int i = lane & 15;

  const unsigned short* qrow = Q + (long)bs * (Hh * Dd) + (kv * Gg + g) * Dd;
  const int ni = 2 * kv + (i >> 3);
  const unsigned short* krow =
      Kf + ((long)bs * Nn + ni) * (KVc * Dd) + (i & 7) * Dd;

  float s = 0.f;
#pragma unroll
  for (int c = 0; c < 16; ++c) {
    uint4 qu = *reinterpret_cast<const uint4*>(qrow + c * 8);
    uint4 ku = *reinterpret_cast<const uint4*>(krow + c * 8);
    s += bf16_lo(qu.x) * bf16_lo(ku.x) + bf16_hi(qu.x) * bf16_hi(ku.x);
    s += bf16_lo(qu.y) * bf16_lo(ku.y) + bf16_hi(qu.y) * bf16_hi(ku.y);
    s += bf16_lo(qu.z) * bf16_lo(ku.z) + bf16_hi(qu.z) * bf16_hi(ku.z);
    s += bf16_lo(qu.w) * bf16_lo(ku.w) + bf16_hi(qu.w) * bf16_hi(ku.w);
  }

  float mx = s;
#pragma unroll
  for (int off = 8; off >= 1; off >>= 1) mx = fmaxf(mx, __shfl_xor(mx, off));
  float p = __expf(s - mx);
  float sum = p;
#pragma unroll
  for (int off = 8; off >= 1; off >>= 1) sum += __shfl_xor(sum, off);
  p = p / sum;

  float o[8] = {0.f, 0.f, 0.f, 0.f, 0.f, 0.f, 0.f, 0.f};
  const long vbase = (long)bs * Nn * (KVc * Dd);
#pragma unroll
  for (int ii = 0; ii < 16; ++ii) {
    float pi = __shfl(p, (lane & 48) | ii);
    const unsigned short* vrow = Vf + vbase +
        (long)(2 * kv + (ii >> 3)) * (KVc * Dd) + (ii & 7) * Dd + i * 8;
    uint4 vu = *reinterpret_cast<const uint4*>(vrow);
    o[0] += pi * bf16_lo(vu.x); o[1] += pi * bf16_hi(vu.x);
    o[2] += pi * bf16_lo(vu.y); o[3] += pi * bf16_hi(vu.y);
    o[4] += pi * bf16_lo(vu.z); o[5] += pi * bf16_hi(vu.z);
    o[6] += pi * bf16_lo(vu.w); o[7] += pi * bf16_hi(vu.w);
  }
  u16x8 ov;
#pragma unroll
  for (int d = 0; d < 8; ++d) ov[d] = f32_to_bf16(o[d]);
  *reinterpret_cast<u16x8*>(O + (long)bs * (Hh * Dd) + (kv * Gg + g) * Dd +
                            i * 8) = ov;
}

// ---------------- launch ----------------
extern "C" void kernel_launch(void* const* d_in, const int* in_sizes, int n_in,
                              void* d_out, int out_size, void* d_ws,
                              size_t ws_size, hipStream_t stream) {
  (void)in_sizes; (void)n_in; (void)out_size; (void)ws_size;
  const float* hs = (const float*)d_in[0];   // [2,2048,4096]
  const float* rhs = (const float*)d_in[1];  // [2,2048,16,1024]
  const float* Wq = (const float*)d_in[2];   // [4096,4096]
  const float* Wk = (const float*)d_in[3];   // [1024,1024]
  const float* Wv = (const float*)d_in[4];   // [1024,1024]
  const float* Wo = (const float*)d_in[5];   // [4096,4096]
  float* out = (float*)d_out;                // [2,2048,4096] f32

  char* ws = (char*)d_ws;
  size_t off = 0;
  auto alloc = [&](size_t bytes) { char* p = ws + off; off += bytes; return p; };
  unsigned short* hsb  = (unsigned short*)alloc(16777216ull * 2);
  unsigned short* Wqb  = (unsigned short*)alloc(16777216ull * 2);
  unsigned short* rhsb = (unsigned short*)alloc(67108864ull * 2);
  unsigned short* Wkb  = (unsigned short*)alloc(1048576ull * 2);
  unsigned short* Wvb  = (unsigned short*)alloc(1048576ull * 2);
  unsigned short* Wob  = (unsigned short*)alloc(16777216ull * 2);
  unsigned short* Qb   = (unsigned short*)alloc(16777216ull * 2);
  unsigned short* Kb   = (unsigned short*)alloc(67108864ull * 2);
  unsigned short* Vb   = (unsigned short*)alloc(67108864ull * 2);
  unsigned short* Ab   = (unsigned short*)alloc(16777216ull * 2);

  const float scaler = 0.08838834764831845f;  // D^-0.5, folded into Wq

  cast_f32_bf16_kernel<<<2048, 256, 0, stream>>>(hs, hsb, 16777216 / 4, 1.f);
  cast_f32_bf16_kernel<<<2048, 256, 0, stream>>>(Wq, Wqb, 16777216 / 4, scaler);
  cast_f32_bf16_kernel<<<4096, 256, 0, stream>>>(rhs, rhsb, 67108864 / 4, 1.f);
  cast_f32_bf16_kernel<<<512, 256, 0, stream>>>(Wk, Wkb, 1048576 / 4, 1.f);
  cast_f32_bf16_kernel<<<512, 256, 0, stream>>>(Wv, Wvb, 1048576 / 4, 1.f);
  cast_f32_bf16_kernel<<<2048, 256, 0, stream>>>(Wo, Wob, 16777216 / 4, 1.f);

  // Q = hs @ Wq^T (scaled), bf16 out   — grid 16x16 = 256 blocks
  gemm256_kernel<true><<<256, 512, 0, stream>>>(hsb, Wqb, Qb, 4096, 4096, 4096);
  // K,V = rhs_flat @ Wk/Wv^T           — grid 256x4 = 1024 blocks
  gemm256_kernel<true><<<1024, 512, 0, stream>>>(rhsb, Wkb, Kb, 65536, 1024, 1024);
  gemm256_kernel<true><<<1024, 512, 0, stream>>>(rhsb, Wvb, Vb, 65536, 1024, 1024);
  // grouped neighbor attention
  attn_kernel<<<8192, 256, 0, stream>>>(Qb, Kb, Vb, Ab);
  // out = attn @ Wo^T, f32 out
  gemm256_kernel<false><<<256, 512, 0, stream>>>(Ab, Wob, out, 4096, 4096, 4096);
}

// Round 6
// 851.410 us; speedup vs baseline: 1.0661x; 1.0661x over previous
//
#include <hip/hip_runtime.h>
#include <hip/hip_bf16.h>
#include <stdint.h>

#define DEV_INLINE __device__ __forceinline__

typedef __attribute__((ext_vector_type(4))) float f32x4;
typedef __attribute__((ext_vector_type(16))) float f32x16;
typedef __attribute__((ext_vector_type(8))) __bf16 bf16x8;
typedef __attribute__((ext_vector_type(8))) unsigned short u16x8;

// problem dims
constexpr int Hh = 32, KVc = 8, Dd = 128, Gg = 4, Nn = 16;

DEV_INLINE unsigned short f32_to_bf16(float f) {
  unsigned u = __float_as_uint(f);
  u += 0x7fffu + ((u >> 16) & 1u);   // round-to-nearest-even
  return (unsigned short)(u >> 16);
}
DEV_INLINE float bf16_lo(unsigned u) { return __uint_as_float(u << 16); }
DEV_INLINE float bf16_hi(unsigned u) { return __uint_as_float(u & 0xffff0000u); }

// ---------------- cast f32 -> bf16 (optionally scaled) ----------------
__global__ void cast_f32_bf16_kernel(const float* __restrict__ src,
                                     unsigned short* __restrict__ dst,
                                     int n4, float scale) {
  int i = blockIdx.x * blockDim.x + threadIdx.x;
  int stride = gridDim.x * blockDim.x;
  const f32x4* s4 = reinterpret_cast<const f32x4*>(src);
  ushort4* d4 = reinterpret_cast<ushort4*>(dst);
  for (; i < n4; i += stride) {
    f32x4 v = s4[i];
    ushort4 o;
    o.x = f32_to_bf16(v.x * scale);
    o.y = f32_to_bf16(v.y * scale);
    o.z = f32_to_bf16(v.z * scale);
    o.w = f32_to_bf16(v.w * scale);
    d4[i] = o;
  }
}

// ---------------- GEMM: C[M][N] = A[M][K] * B[N][K]^T ----------------
// 256x256 tile, BK=32, 512 threads (8 waves 2m x 4n), 32x32x16 MFMA
// (2495 TF pipe ceiling vs 2075 for 16x16; half the MFMA instructions).
// LDS [256 rows][32 k] bf16 with slot swizzle phys = logical ^ (row&3):
// balanced 8-touches-per-bank for the 32x32 fragment read (b128 minimum).
// Ring-4 LDS, stage(t+3) via global_load_lds (inverse-swizzled source,
// linear dest), counted vmcnt(8) once per tile, setprio around MFMA,
// one barrier per tile. Compiler-managed lgkm waits (no inline lgkmcnt).
template <bool OUT_BF16>
__global__ __launch_bounds__(512) void gemm256_kernel(
    const unsigned short* __restrict__ A,   // [M][K] bf16
    const unsigned short* __restrict__ Bw,  // [N][K] bf16
    void* __restrict__ Cout,                // [M][N] f32 or bf16
    int M, int N, int K) {
  __shared__ alignas(16) unsigned short Als[4][8192];  // [slot][256*32] 16 KB
  __shared__ alignas(16) unsigned short Bls[4][8192];
  const int tid = threadIdx.x;
  const int wave = tid >> 6, lane = tid & 63;
  const int wm = wave >> 2, wn = wave & 3;       // 2 x 4 wave grid
  const int l31 = lane & 31, lhi = lane >> 5;
  // swizzled slot byte offsets: logical slot = kk*2 + lhi, phys = log ^ (l&3)
  const int ps0 = ((lhi) ^ (lane & 3)) << 4;     // kk = 0
  const int ps1 = ps0 ^ 32;                      // kk = 1
  const int rbA = wm * 8192 + l31 * 64;          // A row-byte base (m stride 2048)
  const int rbB = wn * 4096 + l31 * 64;          // B row-byte base (n stride 2048)

  // XCD-aware block swizzle (T1); all our grids are % 8 == 0
  const int ntn = N >> 8;
  const int nwg = gridDim.x, bid = blockIdx.x;
  const int swz = (bid & 7) * (nwg >> 3) + (bid >> 3);
  const int tm = swz / ntn, tn = swz - tm * ntn;

  const unsigned short* Abase = A + (long)tm * 256 * K;
  const unsigned short* Bbase = Bw + (long)tn * 256 * K;
  const int ktiles = K >> 5;   // 128 or 32

  // stage one 256x32 tile; linear DMA dest, inverse-swizzled global source.
  // chunk c: row = c>>2, phys slot = c&3, logical = (c&3)^(row&3),
  // k-elem = (logical>>1)*16 + (logical&1)*8
  auto stage = [&](const unsigned short* gbase, unsigned short* lslot, int k0) {
#pragma unroll
    for (int j = 0; j < 2; ++j) {
      int c = (j << 9) + tid;
      int row = c >> 2;
      int lg = (c & 3) ^ (row & 3);
      int koff = ((lg >> 1) << 4) + ((lg & 1) << 3);
      const unsigned short* g = gbase + (long)row * K + k0 + koff;
      int ldsoff = ((j << 9) + (wave << 6)) << 4;  // wave-uniform base
      __builtin_amdgcn_global_load_lds(
          (const __attribute__((address_space(1))) unsigned int*)g,
          (__attribute__((address_space(3))) unsigned int*)((char*)lslot +
                                                            ldsoff),
          16, 0, 0);
    }
  };

  f32x16 acc[4][2];
#pragma unroll
  for (int m = 0; m < 4; ++m)
#pragma unroll
    for (int n = 0; n < 2; ++n)
#pragma unroll
      for (int r = 0; r < 16; ++r) acc[m][n][r] = 0.f;

  // prologue: stage tiles 0..2 (12 loads/thread), wait tile 0 landed
#pragma unroll
  for (int p = 0; p < 3; ++p) {
    if (p < ktiles) {
      stage(Abase, Als[p], p << 5);
      stage(Bbase, Bls[p], p << 5);
    }
  }
  if (ktiles > 2) asm volatile("s_waitcnt vmcnt(8)" ::: "memory");
  else            asm volatile("s_waitcnt vmcnt(0)" ::: "memory");
  __builtin_amdgcn_s_barrier();

  for (int t = 0; t < ktiles; ++t) {
    const char* Ac = (const char*)Als[t & 3];
    const char* Bc = (const char*)Bls[t & 3];
    bf16x8 a0[4], a1[4], b0[2], b1[2];
#pragma unroll
    for (int m = 0; m < 4; ++m) {
      a0[m] = *reinterpret_cast<const bf16x8*>(Ac + rbA + m * 2048 + ps0);
      a1[m] = *reinterpret_cast<const bf16x8*>(Ac + rbA + m * 2048 + ps1);
    }
#pragma unroll
    for (int n = 0; n < 2; ++n) {
      b0[n] = *reinterpret_cast<const bf16x8*>(Bc + rbB + n * 2048 + ps0);
      b1[n] = *reinterpret_cast<const bf16x8*>(Bc + rbB + n * 2048 + ps1);
    }

    if (t + 3 < ktiles) {
      stage(Abase, Als[(t + 3) & 3], (t + 3) << 5);
      stage(Bbase, Bls[(t + 3) & 3], (t + 3) << 5);
    }

    __builtin_amdgcn_s_setprio(1);
#pragma unroll
    for (int m = 0; m < 4; ++m)
#pragma unroll
      for (int n = 0; n < 2; ++n)
        acc[m][n] = __builtin_amdgcn_mfma_f32_32x32x16_bf16(a0[m], b0[n],
                                                            acc[m][n], 0, 0, 0);
#pragma unroll
    for (int m = 0; m < 4; ++m)
#pragma unroll
      for (int n = 0; n < 2; ++n)
        acc[m][n] = __builtin_amdgcn_mfma_f32_32x32x16_bf16(a1[m], b1[n],
                                                            acc[m][n], 0, 0, 0);
    __builtin_amdgcn_s_setprio(0);

    // counted end-of-tile wait: tile t+1 fully in LDS; keep 2 tiles in flight
    if (t + 3 < ktiles)      asm volatile("s_waitcnt vmcnt(8)" ::: "memory");
    else if (t + 2 < ktiles) asm volatile("s_waitcnt vmcnt(4)" ::: "memory");
    else if (t + 1 < ktiles) asm volatile("s_waitcnt vmcnt(0)" ::: "memory");
    __builtin_amdgcn_s_barrier();
  }

  // epilogue (validated r4): col = lane&31, row = (r&3) + 8*(r>>2) + 4*(l>>5)
#pragma unroll
  for (int m = 0; m < 4; ++m) {
#pragma unroll
    for (int n = 0; n < 2; ++n) {
      long c0 = (long)tn * 256 + (wn << 6) + (n << 5) + l31;
      long rb = (long)tm * 256 + (wm << 7) + (m << 5) + (lhi << 2);
#pragma unroll
      for (int r = 0; r < 16; ++r) {
        long row = rb + (r & 3) + ((r >> 2) << 3);
        float v = acc[m][n][r];
        if constexpr (OUT_BF16)
          ((unsigned short*)Cout)[row * N + c0] = f32_to_bf16(v);
        else
          ((float*)Cout)[row * N + c0] = v;
      }
    }
  }
}

// ---------------- grouped neighbor attention ----------------
// one wave per (b*s, kv); lane = g*16 + i
__global__ __launch_bounds__(256) void attn_kernel(
    const unsigned short* __restrict__ Q,   // [B*S][H*D] bf16 (pre-scaled)
    const unsigned short* __restrict__ Kf,  // [B*S*N][KV*D] bf16
    const unsigned short* __restrict__ Vf,  // [B*S*N][KV*D] bf16
    unsigned short* __restrict__ O) {       // [B*S][H*D] bf16
  const int tid = threadIdx.x;
  const int wave = tid >> 6;
  const int lane = tid & 63;
  const int sl = blockIdx.x * 4 + wave;  // [0, B*S*KV)
  const int bs = sl >> 3;
  const int kv = sl & 7;
  const int g = lane >> 4;
  const int i = lane & 15;

  const unsigned short* qrow = Q + (long)bs * (Hh * Dd) + (kv * Gg + g) * Dd;
  const int ni = 2 * kv + (i >> 3);
  const unsigned short* krow =
      Kf + ((long)bs * Nn + ni) * (KVc * Dd) + (i & 7) * Dd;

  float s = 0.f;
#pragma unroll
  for (int c = 0; c < 16; ++c) {
    uint4 qu = *reinterpret_cast<const uint4*>(qrow + c * 8);
    uint4 ku = *reinterpret_cast<const uint4*>(krow + c * 8);
    s += bf16_lo(qu.x) * bf16_lo(ku.x) + bf16_hi(qu.x) * bf16_hi(ku.x);
    s += bf16_lo(qu.y) * bf16_lo(ku.y) + bf16_hi(qu.y) * bf16_hi(ku.y);
    s += bf16_lo(qu.z) * bf16_lo(ku.z) + bf16_hi(qu.z) * bf16_hi(ku.z);
    s += bf16_lo(qu.w) * bf16_lo(ku.w) + bf16_hi(qu.w) * bf16_hi(ku.w);
  }

  float mx = s;
#pragma unroll
  for (int off = 8; off >= 1; off >>= 1) mx = fmaxf(mx, __shfl_xor(mx, off));
  float p = __expf(s - mx);
  float sum = p;
#pragma unroll
  for (int off = 8; off >= 1; off >>= 1) sum += __shfl_xor(sum, off);
  p = p / sum;

  float o[8] = {0.f, 0.f, 0.f, 0.f, 0.f, 0.f, 0.f, 0.f};
  const long vbase = (long)bs * Nn * (KVc * Dd);
#pragma unroll
  for (int ii = 0; ii < 16; ++ii) {
    float pi = __shfl(p, (lane & 48) | ii);
    const unsigned short* vrow = Vf + vbase +
        (long)(2 * kv + (ii >> 3)) * (KVc * Dd) + (ii & 7) * Dd + i * 8;
    uint4 vu = *reinterpret_cast<const uint4*>(vrow);
    o[0] += pi * bf16_lo(vu.x); o[1] += pi * bf16_hi(vu.x);
    o[2] += pi * bf16_lo(vu.y); o[3] += pi * bf16_hi(vu.y);
    o[4] += pi * bf16_lo(vu.z); o[5] += pi * bf16_hi(vu.z);
    o[6] += pi * bf16_lo(vu.w); o[7] += pi * bf16_hi(vu.w);
  }
  u16x8 ov;
#pragma unroll
  for (int d = 0; d < 8; ++d) ov[d] = f32_to_bf16(o[d]);
  *reinterpret_cast<u16x8*>(O + (long)bs * (Hh * Dd) + (kv * Gg + g) * Dd +
                            i * 8) = ov;
}

// ---------------- launch ----------------
extern "C" void kernel_launch(void* const* d_in, const int* in_sizes, int n_in,
                              void* d_out, int out_size, void* d_ws,
                              size_t ws_size, hipStream_t stream) {
  (void)in_sizes; (void)n_in; (void)out_size; (void)ws_size;
  const float* hs = (const float*)d_in[0];   // [2,2048,4096]
  const float* rhs = (const float*)d_in[1];  // [2,2048,16,1024]
  const float* Wq = (const float*)d_in[2];   // [4096,4096]
  const float* Wk = (const float*)d_in[3];   // [1024,1024]
  const float* Wv = (const float*)d_in[4];   // [1024,1024]
  const float* Wo = (const float*)d_in[5];   // [4096,4096]
  float* out = (float*)d_out;                // [2,2048,4096] f32

  char* ws = (char*)d_ws;
  size_t off = 0;
  auto alloc = [&](size_t bytes) { char* p = ws + off; off += bytes; return p; };
  unsigned short* hsb  = (unsigned short*)alloc(16777216ull * 2);
  unsigned short* Wqb  = (unsigned short*)alloc(16777216ull * 2);
  unsigned short* rhsb = (unsigned short*)alloc(67108864ull * 2);
  unsigned short* Wkb  = (unsigned short*)alloc(1048576ull * 2);
  unsigned short* Wvb  = (unsigned short*)alloc(1048576ull * 2);
  unsigned short* Wob  = (unsigned short*)alloc(16777216ull * 2);
  unsigned short* Qb   = (unsigned short*)alloc(16777216ull * 2);
  unsigned short* Kb   = (unsigned short*)alloc(67108864ull * 2);
  unsigned short* Vb   = (unsigned short*)alloc(67108864ull * 2);
  unsigned short* Ab   = (unsigned short*)alloc(16777216ull * 2);

  const float scaler = 0.08838834764831845f;  // D^-0.5, folded into Wq

  cast_f32_bf16_kernel<<<2048, 256, 0, stream>>>(hs, hsb, 16777216 / 4, 1.f);
  cast_f32_bf16_kernel<<<2048, 256, 0, stream>>>(Wq, Wqb, 16777216 / 4, scaler);
  cast_f32_bf16_kernel<<<4096, 256, 0, stream>>>(rhs, rhsb, 67108864 / 4, 1.f);
  cast_f32_bf16_kernel<<<512, 256, 0, stream>>>(Wk, Wkb, 1048576 / 4, 1.f);
  cast_f32_bf16_kernel<<<512, 256, 0, stream>>>(Wv, Wvb, 1048576 / 4, 1.f);
  cast_f32_bf16_kernel<<<2048, 256, 0, stream>>>(Wo, Wob, 16777216 / 4, 1.f);

  // Q = hs @ Wq^T (scaled), bf16 out   — grid 16x16 = 256 blocks
  gemm256_kernel<true><<<256, 512, 0, stream>>>(hsb, Wqb, Qb, 4096, 4096, 4096);
  // K,V = rhs_flat @ Wk/Wv^T           — grid 256x4 = 1024 blocks
  gemm256_kernel<true><<<1024, 512, 0, stream>>>(rhsb, Wkb, Kb, 65536, 1024, 1024);
  gemm256_kernel<true><<<1024, 512, 0, stream>>>(rhsb, Wvb, Vb, 65536, 1024, 1024);
  // grouped neighbor attention
  attn_kernel<<<8192, 256, 0, stream>>>(Qb, Kb, Vb, Ab);
  // out = attn @ Wo^T, f32 out
  gemm256_kernel<false><<<256, 512, 0, stream>>>(Ab, Wob, out, 4096, 4096, 4096);
}